// Round 5
// baseline (245.219 us; speedup 1.0000x reference)
//
#include <hip/hip_runtime.h>

#define N_NODES 50000
#define N_EDGES 640000
#define D 128          // D_IN == D_OUT
#define NB 8           // num bases
#define PAD 64         // bucket slots per dst (mean degree 12.8, 14-sigma headroom)
#define BM 64          // GEMM rows per tile
#define LDA 136        // LDS A row stride in halfs (128+8 pad)
#define OVF_CAP 8192

#define NT_G ((N_NODES + BM - 1) / BM)    // 782 GEMM tiles
#define NT_B ((N_EDGES + 255) / 256)      // 2500 bucket tiles

typedef _Float16 half_t;
typedef __attribute__((ext_vector_type(8))) _Float16 half8;
typedef __attribute__((ext_vector_type(4))) float f32x4;

// ---- k1: zero counters + build Wt/Rt (fp16, transposed) ----
__global__ __launch_bounds__(256)
void init_kernel(const float* __restrict__ bases,
                 const float* __restrict__ comp,
                 const float* __restrict__ root,
                 half_t* __restrict__ Wt,
                 half_t* __restrict__ Rt,
                 int* __restrict__ cnt,
                 int* __restrict__ ovf_cnt) {
    int i = blockIdx.x * 256 + threadIdx.x;
    if (i == 0) *ovf_cnt = 0;
    if (i < N_NODES) cnt[i] = 0;
    if (i < D * D) {
        int ii = i >> 7, o = i & 127;
        float acc = 0.f;
#pragma unroll
        for (int b = 0; b < NB; ++b)
            acc += comp[b] * bases[((size_t)b * D + ii) * D + o];
        Wt[o * D + ii] = (half_t)acc;
        Rt[o * D + ii] = (half_t)root[i];
    }
}

// ---- k2: GEMM tiles + bucket tiles fused, interleaved 1:3, no dependency ----
__global__ __launch_bounds__(256)
void gemm_bucket_kernel(const float* __restrict__ x,
                        const int* __restrict__ eidx,
                        const half_t* __restrict__ Wt,   // [n][k]
                        const half_t* __restrict__ Rt,   // [n][k]
                        const float* __restrict__ bias,
                        half_t* __restrict__ y,
                        float* __restrict__ out,
                        int* __restrict__ cnt,
                        int* __restrict__ bucket,
                        int* __restrict__ ovf_cnt,
                        int2* __restrict__ ovf) {
    __shared__ __align__(16) half_t As[BM * LDA];
    const int tid = threadIdx.x;
    const int t = blockIdx.x;

    // interleave: groups of 4 blocks = 1 gemm + 3 bucket, then leftover bucket
    int gemm_tile = -1, bucket_tile = -1;
    if (t < NT_G * 4) {
        int g = t >> 2, r = t & 3;
        if (r == 0) gemm_tile = g;
        else        bucket_tile = g * 3 + (r - 1);
    } else {
        bucket_tile = NT_G * 3 + (t - NT_G * 4);
    }

    if (gemm_tile >= 0) {
        const int row0 = gemm_tile * BM;
        {   // stage 64 rows of x, fp32 -> fp16
            int r  = tid >> 2;
            int cc = (tid & 3) * 32;
            if (row0 + r < N_NODES) {
                const float4* x4 = (const float4*)x;
                size_t base = (size_t)(row0 + r) * 32 + (cc >> 2);
#pragma unroll
                for (int u = 0; u < 4; ++u) {
                    float4 v0 = x4[base + 2 * u];
                    float4 v1 = x4[base + 2 * u + 1];
                    half8 h;
                    h[0] = (half_t)v0.x; h[1] = (half_t)v0.y;
                    h[2] = (half_t)v0.z; h[3] = (half_t)v0.w;
                    h[4] = (half_t)v1.x; h[5] = (half_t)v1.y;
                    h[6] = (half_t)v1.z; h[7] = (half_t)v1.w;
                    *(half8*)&As[r * LDA + cc + u * 8] = h;
                }
            }
        }
        __syncthreads();

        const int wave = tid >> 6;
        const int lane = tid & 63;
        const int m    = lane & 15;
        const int quad = lane >> 4;

        half8 a[4];
#pragma unroll
        for (int kk = 0; kk < 4; ++kk)
            a[kk] = *(const half8*)&As[(wave * 16 + m) * LDA + kk * 32 + quad * 8];

        f32x4 accW[8], accR[8];
#pragma unroll
        for (int nt = 0; nt < 8; ++nt) {
            accW[nt] = (f32x4){0.f, 0.f, 0.f, 0.f};
            accR[nt] = (f32x4){0.f, 0.f, 0.f, 0.f};
        }
#pragma unroll
        for (int nt = 0; nt < 8; ++nt) {
            const half_t* wp = Wt + (nt * 16 + m) * D + quad * 8;
            const half_t* rp = Rt + (nt * 16 + m) * D + quad * 8;
            half8 bw[4], br[4];
#pragma unroll
            for (int kk = 0; kk < 4; ++kk) {
                bw[kk] = *(const half8*)(wp + kk * 32);
                br[kk] = *(const half8*)(rp + kk * 32);
            }
#pragma unroll
            for (int kk = 0; kk < 4; ++kk) {
                accW[nt] = __builtin_amdgcn_mfma_f32_16x16x32_f16(a[kk], bw[kk], accW[nt], 0, 0, 0);
                accR[nt] = __builtin_amdgcn_mfma_f32_16x16x32_f16(a[kk], br[kk], accR[nt], 0, 0, 0);
            }
        }
        // C/D layout: col = lane&15, row = quad*4 + reg
#pragma unroll
        for (int nt = 0; nt < 8; ++nt) {
            int col = nt * 16 + m;
            float bb = bias[col];
#pragma unroll
            for (int r = 0; r < 4; ++r) {
                int row = row0 + wave * 16 + quad * 4 + r;
                if (row < N_NODES) {
                    y[(size_t)row * D + col]   = (half_t)accW[nt][r];
                    out[(size_t)row * D + col] = accR[nt][r] + bb;
                }
            }
        }
    } else {
        // ---- bucket tile: 256 edges, one int atomic each ----
        int e = bucket_tile * 256 + tid;
        if (e < N_EDGES) {
            int src = eidx[e];
            int dst = eidx[N_EDGES + e];
            int pos = atomicAdd(&cnt[dst], 1);
            if (pos < PAD) {
                bucket[(size_t)dst * PAD + pos] = src;
            } else {                 // ~never (P<1e-20); drained by k4
                int op = atomicAdd(ovf_cnt, 1);
                if (op < OVF_CAP) ovf[op] = make_int2(dst, src);
            }
        }
    }
}

// ---- k3: gather, 16 lanes per node, 8 rows in flight ----
__global__ __launch_bounds__(256)
void gather_kernel(const int* __restrict__ cnt,
                   const int* __restrict__ bucket,
                   const half_t* __restrict__ y,
                   float* __restrict__ out) {
    int node = blockIdx.x * 16 + (threadIdx.x >> 4);
    int q = threadIdx.x & 15;
    if (node >= N_NODES) return;
    int c = cnt[node];
    if (c > PAD) c = PAD;
    const int* b = bucket + (size_t)node * PAD;
    float acc[8] = {0.f, 0.f, 0.f, 0.f, 0.f, 0.f, 0.f, 0.f};
    int i = 0;
    for (; i + 8 <= c; i += 8) {
        int4 s0 = *(const int4*)(b + i);
        int4 s1 = *(const int4*)(b + i + 4);
        half8 v0 = *(const half8*)(y + (size_t)s0.x * D + q * 8);
        half8 v1 = *(const half8*)(y + (size_t)s0.y * D + q * 8);
        half8 v2 = *(const half8*)(y + (size_t)s0.z * D + q * 8);
        half8 v3 = *(const half8*)(y + (size_t)s0.w * D + q * 8);
        half8 v4 = *(const half8*)(y + (size_t)s1.x * D + q * 8);
        half8 v5 = *(const half8*)(y + (size_t)s1.y * D + q * 8);
        half8 v6 = *(const half8*)(y + (size_t)s1.z * D + q * 8);
        half8 v7 = *(const half8*)(y + (size_t)s1.w * D + q * 8);
#pragma unroll
        for (int j = 0; j < 8; ++j)
            acc[j] += ((float)v0[j] + (float)v1[j]) + ((float)v2[j] + (float)v3[j])
                    + ((float)v4[j] + (float)v5[j]) + ((float)v6[j] + (float)v7[j]);
    }
    for (; i + 4 <= c; i += 4) {
        int4 s = *(const int4*)(b + i);
        half8 v0 = *(const half8*)(y + (size_t)s.x * D + q * 8);
        half8 v1 = *(const half8*)(y + (size_t)s.y * D + q * 8);
        half8 v2 = *(const half8*)(y + (size_t)s.z * D + q * 8);
        half8 v3 = *(const half8*)(y + (size_t)s.w * D + q * 8);
#pragma unroll
        for (int j = 0; j < 8; ++j)
            acc[j] += ((float)v0[j] + (float)v1[j]) + ((float)v2[j] + (float)v3[j]);
    }
    for (; i < c; ++i) {
        half8 v = *(const half8*)(y + (size_t)b[i] * D + q * 8);
#pragma unroll
        for (int j = 0; j < 8; ++j) acc[j] += (float)v[j];
    }
    float4* op = (float4*)(out + (size_t)node * D + q * 8);
    float4 o0 = op[0], o1 = op[1];
    o0.x += acc[0]; o0.y += acc[1]; o0.z += acc[2]; o0.w += acc[3];
    o1.x += acc[4]; o1.y += acc[5]; o1.z += acc[6]; o1.w += acc[7];
    op[0] = o0; op[1] = o1;
}

// ---- k4: drain overflow list (deterministically empty; correct if not) ----
__global__ __launch_bounds__(256)
void ovf_drain_kernel(const int* __restrict__ ovf_cnt,
                      const int2* __restrict__ ovf,
                      const half_t* __restrict__ y,
                      float* __restrict__ out) {
    int novf = *ovf_cnt;
    if (novf > OVF_CAP) novf = OVF_CAP;
    int total = novf * D;
    for (int w = blockIdx.x * 256 + threadIdx.x; w < total; w += gridDim.x * 256) {
        int e = w >> 7, qq = w & 127;
        atomicAdd(out + (size_t)ovf[e].x * D + qq,
                  (float)y[(size_t)ovf[e].y * D + qq]);
    }
}

extern "C" void kernel_launch(void* const* d_in, const int* in_sizes, int n_in,
                              void* d_out, int out_size, void* d_ws, size_t ws_size,
                              hipStream_t stream) {
    const float* x     = (const float*)d_in[0];
    const int*   eidx  = (const int*)d_in[1];
    const float* bases = (const float*)d_in[2];
    const float* comp  = (const float*)d_in[3];
    const float* root  = (const float*)d_in[4];
    const float* bias  = (const float*)d_in[5];
    float* out = (float*)d_out;

    char* ws = (char*)d_ws;
    half_t* y       = (half_t*)ws;                      // 12,800,000 B
    half_t* Wt      = (half_t*)(ws + 12800000);         //     32,768 B
    half_t* Rt      = (half_t*)(ws + 12832768);         //     32,768 B
    int*    cnt     = (int*)   (ws + 12865536);         //    200,000 B
    int*    bucket  = (int*)   (ws + 13065536);         // 12,800,000 B
    int*    ovf_cnt = (int*)   (ws + 25865536);         //         64 B
    int2*   ovf     = (int2*)  (ws + 25865600);         //     65,536 B

    init_kernel<<<(N_NODES + 255) / 256, 256, 0, stream>>>(
        bases, comp, root, Wt, Rt, cnt, ovf_cnt);
    gemm_bucket_kernel<<<NT_G * 4 + (NT_B - NT_G * 3), 256, 0, stream>>>(
        x, eidx, Wt, Rt, bias, y, out, cnt, bucket, ovf_cnt, ovf);
    gather_kernel<<<(N_NODES + 15) / 16, 256, 0, stream>>>(cnt, bucket, y, out);
    ovf_drain_kernel<<<32, 256, 0, stream>>>(ovf_cnt, ovf, y, out);
}

// Round 6
// 181.924 us; speedup vs baseline: 1.3479x; 1.3479x over previous
//
#include <hip/hip_runtime.h>

#define N_NODES 50000
#define N_EDGES 640000
#define D 128          // D_IN == D_OUT
#define NB 8           // num bases
#define PAD 32         // bucket slots per dst (mean deg 12.8; overflow -> direct atomics)
#define BM 64          // GEMM rows per block (4 waves x 16)

typedef _Float16 half_t;
typedef __attribute__((ext_vector_type(8))) _Float16 half8;
typedef __attribute__((ext_vector_type(4))) float f32x4;

// ---- k1: zero counters + build Wt/Rt (fp16, transposed [n][k]) ----
__global__ __launch_bounds__(256)
void init_kernel(const float* __restrict__ bases,
                 const float* __restrict__ comp,
                 const float* __restrict__ root,
                 half_t* __restrict__ Wt,
                 half_t* __restrict__ Rt,
                 int* __restrict__ cnt) {
    int i = blockIdx.x * 256 + threadIdx.x;
    if (i < N_NODES) cnt[i] = 0;
    if (i < D * D) {
        int ii = i >> 7, o = i & 127;
        float acc = 0.f;
#pragma unroll
        for (int b = 0; b < NB; ++b)
            acc += comp[b] * bases[((size_t)b * D + ii) * D + o];
        Wt[o * D + ii] = (half_t)acc;
        Rt[o * D + ii] = (half_t)root[i];
    }
}

// ---- k2: y(half) = x@W ; out(f32) = x@root + bias. No LDS, no barrier. ----
// Lane (m, quad) of wave w loads its own A-row fragment straight from x.
__global__ __launch_bounds__(256)
void gemm_kernel(const float* __restrict__ x,
                 const half_t* __restrict__ Wt,   // [n][k]
                 const half_t* __restrict__ Rt,   // [n][k]
                 const float* __restrict__ bias,
                 half_t* __restrict__ y,
                 float* __restrict__ out) {
    const int tid  = threadIdx.x;
    const int wave = tid >> 6;
    const int lane = tid & 63;
    const int m    = lane & 15;
    const int quad = lane >> 4;
    const int row0 = blockIdx.x * BM;
    const int arow = row0 + wave * 16 + m;

    // A fragment: A[m][k], k = quad*8 + j per K-step; 8 independent float4 loads
    const float4* x4 = (const float4*)x;
    size_t abase = (size_t)(arow < N_NODES ? arow : 0) * 32 + quad * 2;
    float4 xa[8];
#pragma unroll
    for (int kk = 0; kk < 4; ++kk) {
        xa[2 * kk]     = x4[abase + kk * 8];
        xa[2 * kk + 1] = x4[abase + kk * 8 + 1];
    }
    half8 a[4];
#pragma unroll
    for (int kk = 0; kk < 4; ++kk) {
        float4 v0 = xa[2 * kk], v1 = xa[2 * kk + 1];
        half8 h;
        h[0] = (half_t)v0.x; h[1] = (half_t)v0.y; h[2] = (half_t)v0.z; h[3] = (half_t)v0.w;
        h[4] = (half_t)v1.x; h[5] = (half_t)v1.y; h[6] = (half_t)v1.z; h[7] = (half_t)v1.w;
        a[kk] = h;
    }

    f32x4 accW[8], accR[8];
#pragma unroll
    for (int nt = 0; nt < 8; ++nt) {
        accW[nt] = (f32x4){0.f, 0.f, 0.f, 0.f};
        accR[nt] = (f32x4){0.f, 0.f, 0.f, 0.f};
    }
#pragma unroll
    for (int nt = 0; nt < 8; ++nt) {
        // B frags: B[k][n], n = lane&15, k = quad*8 + j; Wt/Rt row-major [n][k]
        const half_t* wp = Wt + (nt * 16 + m) * D + quad * 8;
        const half_t* rp = Rt + (nt * 16 + m) * D + quad * 8;
        half8 bw[4], br[4];
#pragma unroll
        for (int kk = 0; kk < 4; ++kk) {
            bw[kk] = *(const half8*)(wp + kk * 32);
            br[kk] = *(const half8*)(rp + kk * 32);
        }
#pragma unroll
        for (int kk = 0; kk < 4; ++kk) {
            accW[nt] = __builtin_amdgcn_mfma_f32_16x16x32_f16(a[kk], bw[kk], accW[nt], 0, 0, 0);
            accR[nt] = __builtin_amdgcn_mfma_f32_16x16x32_f16(a[kk], br[kk], accR[nt], 0, 0, 0);
        }
    }
    // C/D layout: col = lane&15, row = quad*4 + reg
#pragma unroll
    for (int nt = 0; nt < 8; ++nt) {
        int col = nt * 16 + m;
        float bb = bias[col];
#pragma unroll
        for (int r = 0; r < 4; ++r) {
            int row = row0 + wave * 16 + quad * 4 + r;
            if (row < N_NODES) {
                y[(size_t)row * D + col]   = (half_t)accW[nt][r];
                out[(size_t)row * D + col] = accR[nt][r] + bb;
            }
        }
    }
}

// ---- k3 (after gemm): bucket edges; overflow -> direct atomics into out ----
__global__ __launch_bounds__(256)
void bucket_kernel(const int* __restrict__ eidx,
                   const half_t* __restrict__ y,
                   float* __restrict__ out,
                   int* __restrict__ cnt,
                   int* __restrict__ bucket) {
    int e = blockIdx.x * 256 + threadIdx.x;
    if (e >= N_EDGES) return;
    int src = eidx[e];
    int dst = eidx[N_EDGES + e];
    int pos = atomicAdd(&cnt[dst], 1);
    if (pos < PAD) {
        bucket[(size_t)dst * PAD + pos] = src;
    } else {   // P ~ 1e-7 per node; correct fallback (y/out already written by gemm)
        const half_t* yr = y + (size_t)src * D;
        float* op = out + (size_t)dst * D;
        for (int q = 0; q < D; ++q) atomicAdd(op + q, (float)yr[q]);
    }
}

// ---- k4: gather, 16 lanes per node, 8 rows in flight ----
__global__ __launch_bounds__(256)
void gather_kernel(const int* __restrict__ cnt,
                   const int* __restrict__ bucket,
                   const half_t* __restrict__ y,
                   float* __restrict__ out) {
    int node = blockIdx.x * 16 + (threadIdx.x >> 4);
    int q = threadIdx.x & 15;
    if (node >= N_NODES) return;
    int c = cnt[node];
    if (c > PAD) c = PAD;
    const int* b = bucket + (size_t)node * PAD;
    float acc[8] = {0.f, 0.f, 0.f, 0.f, 0.f, 0.f, 0.f, 0.f};
    int i = 0;
    for (; i + 8 <= c; i += 8) {
        int4 s0 = *(const int4*)(b + i);
        int4 s1 = *(const int4*)(b + i + 4);
        half8 v0 = *(const half8*)(y + (size_t)s0.x * D + q * 8);
        half8 v1 = *(const half8*)(y + (size_t)s0.y * D + q * 8);
        half8 v2 = *(const half8*)(y + (size_t)s0.z * D + q * 8);
        half8 v3 = *(const half8*)(y + (size_t)s0.w * D + q * 8);
        half8 v4 = *(const half8*)(y + (size_t)s1.x * D + q * 8);
        half8 v5 = *(const half8*)(y + (size_t)s1.y * D + q * 8);
        half8 v6 = *(const half8*)(y + (size_t)s1.z * D + q * 8);
        half8 v7 = *(const half8*)(y + (size_t)s1.w * D + q * 8);
#pragma unroll
        for (int j = 0; j < 8; ++j)
            acc[j] += ((float)v0[j] + (float)v1[j]) + ((float)v2[j] + (float)v3[j])
                    + ((float)v4[j] + (float)v5[j]) + ((float)v6[j] + (float)v7[j]);
    }
    for (; i + 4 <= c; i += 4) {
        int4 s = *(const int4*)(b + i);
        half8 v0 = *(const half8*)(y + (size_t)s.x * D + q * 8);
        half8 v1 = *(const half8*)(y + (size_t)s.y * D + q * 8);
        half8 v2 = *(const half8*)(y + (size_t)s.z * D + q * 8);
        half8 v3 = *(const half8*)(y + (size_t)s.w * D + q * 8);
#pragma unroll
        for (int j = 0; j < 8; ++j)
            acc[j] += ((float)v0[j] + (float)v1[j]) + ((float)v2[j] + (float)v3[j]);
    }
    for (; i < c; ++i) {
        half8 v = *(const half8*)(y + (size_t)b[i] * D + q * 8);
#pragma unroll
        for (int j = 0; j < 8; ++j) acc[j] += (float)v[j];
    }
    float4* op = (float4*)(out + (size_t)node * D + q * 8);
    float4 o0 = op[0], o1 = op[1];
    o0.x += acc[0]; o0.y += acc[1]; o0.z += acc[2]; o0.w += acc[3];
    o1.x += acc[4]; o1.y += acc[5]; o1.z += acc[6]; o1.w += acc[7];
    op[0] = o0; op[1] = o1;
}

extern "C" void kernel_launch(void* const* d_in, const int* in_sizes, int n_in,
                              void* d_out, int out_size, void* d_ws, size_t ws_size,
                              hipStream_t stream) {
    const float* x     = (const float*)d_in[0];
    const int*   eidx  = (const int*)d_in[1];
    const float* bases = (const float*)d_in[2];
    const float* comp  = (const float*)d_in[3];
    const float* root  = (const float*)d_in[4];
    const float* bias  = (const float*)d_in[5];
    float* out = (float*)d_out;

    char* ws = (char*)d_ws;
    half_t* y      = (half_t*)ws;                      // 12,800,000 B
    half_t* Wt     = (half_t*)(ws + 12800000);         //     32,768 B
    half_t* Rt     = (half_t*)(ws + 12832768);         //     32,768 B
    int*    cnt    = (int*)   (ws + 12865536);         //    200,000 B
    int*    bucket = (int*)   (ws + 13065536);         //  6,400,000 B

    init_kernel<<<(N_NODES + 255) / 256, 256, 0, stream>>>(
        bases, comp, root, Wt, Rt, cnt);
    gemm_kernel<<<(N_NODES + BM - 1) / BM, 256, 0, stream>>>(
        x, Wt, Rt, bias, y, out);
    bucket_kernel<<<(N_EDGES + 255) / 256, 256, 0, stream>>>(
        eidx, y, out, cnt, bucket);
    gather_kernel<<<(N_NODES + 15) / 16, 256, 0, stream>>>(
        cnt, bucket, y, out);
}

// Round 7
// 167.931 us; speedup vs baseline: 1.4602x; 1.0833x over previous
//
#include <hip/hip_runtime.h>

#define N_NODES 50000
#define N_EDGES 640000
#define D 128          // D_IN == D_OUT
#define NB 8           // num bases
#define PAD 32         // bucket slots per dst (mean deg 12.8; overflow -> direct atomics)
#define NSTRIP 3125    // 50000 / 16 row-strips
#define GRID_G 1024    // gemm blocks: 4096 waves, exactly resident at 4 waves/SIMD

typedef _Float16 half_t;
typedef __attribute__((ext_vector_type(8))) _Float16 half8;
typedef __attribute__((ext_vector_type(4))) float f32x4;

// ---- k1: zero counters + build Wt/Rt (fp16, transposed [n][k]) ----
__global__ __launch_bounds__(256)
void init_kernel(const float* __restrict__ bases,
                 const float* __restrict__ comp,
                 const float* __restrict__ root,
                 half_t* __restrict__ Wt,
                 half_t* __restrict__ Rt,
                 int* __restrict__ cnt) {
    int i = blockIdx.x * 256 + threadIdx.x;
    if (i < N_NODES) cnt[i] = 0;
    if (i < D * D) {
        int ii = i >> 7, o = i & 127;
        float acc = 0.f;
#pragma unroll
        for (int b = 0; b < NB; ++b)
            acc += comp[b] * bases[((size_t)b * D + ii) * D + o];
        Wt[o * D + ii] = (half_t)acc;
        Rt[o * D + ii] = (half_t)root[i];
    }
}

// ---- k2: y(half) = x@W ; out(f32) = x@root + bias ----
// Each wave: 32-col quarter of BOTH matrices resident in regs (16 half8),
// grid-strides over 16-row M-strips. VGPR budget ~120 -> 4 waves/SIMD.
__global__ __launch_bounds__(256, 4)
void gemm_kernel(const float* __restrict__ x,
                 const half_t* __restrict__ Wt,   // [n][k]
                 const half_t* __restrict__ Rt,   // [n][k]
                 const float* __restrict__ bias,
                 half_t* __restrict__ y,
                 float* __restrict__ out) {
    const int tid  = threadIdx.x;
    const int wave = tid >> 6;
    const int lane = tid & 63;
    const int m    = lane & 15;
    const int quad = lane >> 4;
    const int gw   = blockIdx.x * 4 + wave;
    const int q    = gw & 3;                 // col quarter: nt = 2q, 2q+1
    const int s0   = gw >> 2;                // starting M-strip
    const int SSTR = GRID_G;                 // (GRID_G*4)/4 strips stride

    // B fragments, loaded ONCE: B[k][n], n = lane&15, k = quad*8 + j
    half8 bw[2][4], br[2][4];
    float bb[2];
#pragma unroll
    for (int t = 0; t < 2; ++t) {
        const int nt = 2 * q + t;
        const half_t* wp = Wt + (nt * 16 + m) * D + quad * 8;
        const half_t* rp = Rt + (nt * 16 + m) * D + quad * 8;
#pragma unroll
        for (int kk = 0; kk < 4; ++kk) {
            bw[t][kk] = *(const half8*)(wp + kk * 32);
            br[t][kk] = *(const half8*)(rp + kk * 32);
        }
        bb[t] = bias[nt * 16 + m];
    }

    const float4* x4 = (const float4*)x;
    for (int s = s0; s < NSTRIP; s += SSTR) {
        // A fragment: A[m][k], row = s*16 + m, k = quad*8 + j
        size_t ab = (size_t)(s * 16 + m) * 32 + quad * 2;
        half8 a[4];
#pragma unroll
        for (int kk = 0; kk < 4; ++kk) {
            float4 v0 = x4[ab + kk * 8];
            float4 v1 = x4[ab + kk * 8 + 1];
            half8 h;
            h[0] = (half_t)v0.x; h[1] = (half_t)v0.y; h[2] = (half_t)v0.z; h[3] = (half_t)v0.w;
            h[4] = (half_t)v1.x; h[5] = (half_t)v1.y; h[6] = (half_t)v1.z; h[7] = (half_t)v1.w;
            a[kk] = h;
        }

        f32x4 accW[2], accR[2];
#pragma unroll
        for (int t = 0; t < 2; ++t) {
            accW[t] = (f32x4){0.f, 0.f, 0.f, 0.f};
            accR[t] = (f32x4){0.f, 0.f, 0.f, 0.f};
        }
#pragma unroll
        for (int t = 0; t < 2; ++t)
#pragma unroll
            for (int kk = 0; kk < 4; ++kk) {
                accW[t] = __builtin_amdgcn_mfma_f32_16x16x32_f16(a[kk], bw[t][kk], accW[t], 0, 0, 0);
                accR[t] = __builtin_amdgcn_mfma_f32_16x16x32_f16(a[kk], br[t][kk], accR[t], 0, 0, 0);
            }

        // C/D layout: col = lane&15, row = quad*4 + reg
#pragma unroll
        for (int t = 0; t < 2; ++t) {
            int col = (2 * q + t) * 16 + m;
#pragma unroll
            for (int r = 0; r < 4; ++r) {
                int row = s * 16 + quad * 4 + r;
                y[(size_t)row * D + col]   = (half_t)accW[t][r];
                out[(size_t)row * D + col] = accR[t][r] + bb[t];
            }
        }
    }
}

// ---- k3 (after gemm): bucket edges; overflow -> direct atomics into out ----
__global__ __launch_bounds__(256)
void bucket_kernel(const int* __restrict__ eidx,
                   const half_t* __restrict__ y,
                   float* __restrict__ out,
                   int* __restrict__ cnt,
                   int* __restrict__ bucket) {
    int e = blockIdx.x * 256 + threadIdx.x;
    if (e >= N_EDGES) return;
    int src = eidx[e];
    int dst = eidx[N_EDGES + e];
    int pos = atomicAdd(&cnt[dst], 1);
    if (pos < PAD) {
        bucket[(size_t)dst * PAD + pos] = src;
    } else {   // P ~ 1e-7 per node; correct fallback (y/out already written by gemm)
        const half_t* yr = y + (size_t)src * D;
        float* op = out + (size_t)dst * D;
        for (int q = 0; q < D; ++q) atomicAdd(op + q, (float)yr[q]);
    }
}

// ---- k4: gather, 16 lanes per node, 8 rows in flight ----
__global__ __launch_bounds__(256)
void gather_kernel(const int* __restrict__ cnt,
                   const int* __restrict__ bucket,
                   const half_t* __restrict__ y,
                   float* __restrict__ out) {
    int node = blockIdx.x * 16 + (threadIdx.x >> 4);
    int q = threadIdx.x & 15;
    if (node >= N_NODES) return;
    int c = cnt[node];
    if (c > PAD) c = PAD;
    const int* b = bucket + (size_t)node * PAD;
    float acc[8] = {0.f, 0.f, 0.f, 0.f, 0.f, 0.f, 0.f, 0.f};
    int i = 0;
    for (; i + 8 <= c; i += 8) {
        int4 s0 = *(const int4*)(b + i);
        int4 s1 = *(const int4*)(b + i + 4);
        half8 v0 = *(const half8*)(y + (size_t)s0.x * D + q * 8);
        half8 v1 = *(const half8*)(y + (size_t)s0.y * D + q * 8);
        half8 v2 = *(const half8*)(y + (size_t)s0.z * D + q * 8);
        half8 v3 = *(const half8*)(y + (size_t)s0.w * D + q * 8);
        half8 v4 = *(const half8*)(y + (size_t)s1.x * D + q * 8);
        half8 v5 = *(const half8*)(y + (size_t)s1.y * D + q * 8);
        half8 v6 = *(const half8*)(y + (size_t)s1.z * D + q * 8);
        half8 v7 = *(const half8*)(y + (size_t)s1.w * D + q * 8);
#pragma unroll
        for (int j = 0; j < 8; ++j)
            acc[j] += ((float)v0[j] + (float)v1[j]) + ((float)v2[j] + (float)v3[j])
                    + ((float)v4[j] + (float)v5[j]) + ((float)v6[j] + (float)v7[j]);
    }
    for (; i + 4 <= c; i += 4) {
        int4 s = *(const int4*)(b + i);
        half8 v0 = *(const half8*)(y + (size_t)s.x * D + q * 8);
        half8 v1 = *(const half8*)(y + (size_t)s.y * D + q * 8);
        half8 v2 = *(const half8*)(y + (size_t)s.z * D + q * 8);
        half8 v3 = *(const half8*)(y + (size_t)s.w * D + q * 8);
#pragma unroll
        for (int j = 0; j < 8; ++j)
            acc[j] += ((float)v0[j] + (float)v1[j]) + ((float)v2[j] + (float)v3[j]);
    }
    for (; i < c; ++i) {
        half8 v = *(const half8*)(y + (size_t)b[i] * D + q * 8);
#pragma unroll
        for (int j = 0; j < 8; ++j) acc[j] += (float)v[j];
    }
    float4* op = (float4*)(out + (size_t)node * D + q * 8);
    float4 o0 = op[0], o1 = op[1];
    o0.x += acc[0]; o0.y += acc[1]; o0.z += acc[2]; o0.w += acc[3];
    o1.x += acc[4]; o1.y += acc[5]; o1.z += acc[6]; o1.w += acc[7];
    op[0] = o0; op[1] = o1;
}

extern "C" void kernel_launch(void* const* d_in, const int* in_sizes, int n_in,
                              void* d_out, int out_size, void* d_ws, size_t ws_size,
                              hipStream_t stream) {
    const float* x     = (const float*)d_in[0];
    const int*   eidx  = (const int*)d_in[1];
    const float* bases = (const float*)d_in[2];
    const float* comp  = (const float*)d_in[3];
    const float* root  = (const float*)d_in[4];
    const float* bias  = (const float*)d_in[5];
    float* out = (float*)d_out;

    char* ws = (char*)d_ws;
    half_t* y      = (half_t*)ws;                      // 12,800,000 B
    half_t* Wt     = (half_t*)(ws + 12800000);         //     32,768 B
    half_t* Rt     = (half_t*)(ws + 12832768);         //     32,768 B
    int*    cnt    = (int*)   (ws + 12865536);         //    200,000 B
    int*    bucket = (int*)   (ws + 13065536);         //  6,400,000 B

    init_kernel<<<(N_NODES + 255) / 256, 256, 0, stream>>>(
        bases, comp, root, Wt, Rt, cnt);
    gemm_kernel<<<GRID_G, 256, 0, stream>>>(
        x, Wt, Rt, bias, y, out);
    bucket_kernel<<<(N_EDGES + 255) / 256, 256, 0, stream>>>(
        eidx, y, out, cnt, bucket);
    gather_kernel<<<(N_NODES + 15) / 16, 256, 0, stream>>>(
        cnt, bucket, y, out);
}